// Round 6
// baseline (353.786 us; speedup 1.0000x reference)
//
#include <hip/hip_runtime.h>

#define TT 4096
#define T1 4097

using f32x4 = __attribute__((ext_vector_type(4))) float;

// ---------------- batched GEMV: Y[b][j] += sum_k X[b][k] * W[k][j], all f32 --------
// block 256: ct = tid&7 (4 cols -> 32 cols/block), kt = tid>>3 (32-way k parallel)
// grid (N/32, KS); chunk = K/KS. Y pre-zeroed, atomically accumulated.
__global__ __launch_bounds__(256) void gemv_atomic(const float* __restrict__ X,
                                                   const float* __restrict__ W,
                                                   float* __restrict__ Y,
                                                   int N, int K, int chunk) {
  const int tid = threadIdx.x;
  const int ct = tid & 7;
  const int kt = tid >> 3;
  const int col0 = blockIdx.x * 32 + ct * 4;
  const int k0 = blockIdx.y * chunk;
  float acc[4][4];
#pragma unroll
  for (int c = 0; c < 4; ++c)
#pragma unroll
    for (int b = 0; b < 4; ++b) acc[c][b] = 0.f;
  const int iters = chunk >> 5;
  for (int i = 0; i < iters; ++i) {
    int k = k0 + kt + (i << 5);
    f32x4 w4 = *(const f32x4*)(W + (size_t)k * N + col0);
    float xb[4];
#pragma unroll
    for (int b = 0; b < 4; ++b) xb[b] = X[(size_t)b * K + k];
#pragma unroll
    for (int c = 0; c < 4; ++c)
#pragma unroll
      for (int b = 0; b < 4; ++b) acc[c][b] += w4[c] * xb[b];
  }
  __shared__ float red[256][16];
#pragma unroll
  for (int c = 0; c < 4; ++c)
#pragma unroll
    for (int b = 0; b < 4; ++b) red[tid][c * 4 + b] = acc[c][b];
  __syncthreads();
  for (int s = 16; s >= 1; s >>= 1) {
    if (kt < s) {
#pragma unroll
      for (int j = 0; j < 16; ++j) red[tid][j] += red[tid + 8 * s][j];
    }
    __syncthreads();
  }
  if (kt == 0) {
#pragma unroll
    for (int c = 0; c < 4; ++c)
#pragma unroll
      for (int b = 0; b < 4; ++b)
        atomicAdd(&Y[(size_t)b * N + col0 + c], red[ct][c * 4 + b]);
  }
}

// ---------------- absorb: q_abs[b][n][v] = sum_d qC[b][n][d] * W_UK[v][n][d] ------
// grid (32 n, 4 vt); block 128: one thread per v
__global__ __launch_bounds__(128) void absorb_kernel(const float* __restrict__ qC,
                                                     const float* __restrict__ W_UK,
                                                     float* __restrict__ q_abs) {
  const int n = blockIdx.x, vt = blockIdx.y;
  __shared__ float qs[4][128];
  for (int i = threadIdx.x; i < 512; i += 128)
    qs[i >> 7][i & 127] = qC[(size_t)(i >> 7) * 4096 + n * 128 + (i & 127)];
  __syncthreads();
  const int v = vt * 128 + threadIdx.x;
  const float* wp = W_UK + (size_t)v * 4096 + n * 128;
  float acc[4] = {0.f, 0.f, 0.f, 0.f};
#pragma unroll 8
  for (int c = 0; c < 32; ++c) {
    f32x4 w4 = *(const f32x4*)(wp + c * 4);
#pragma unroll
    for (int j = 0; j < 4; ++j)
#pragma unroll
      for (int b = 0; b < 4; ++b) acc[b] += qs[b][c * 4 + j] * w4[j];
  }
#pragma unroll
  for (int b = 0; b < 4; ++b) q_abs[((size_t)(b * 32) + n) * 512 + v] = acc[b];
}

// ---------------- prefix scores (no copy) -----------------------------------------
// grid (512 t-tiles of 8, 4 b); block 256: n = tid&31, tg = tid>>5 (1 t each)
__global__ __launch_bounds__(256) void scores_kernel(const float* __restrict__ cKV,
                                                     const float* __restrict__ kR,
                                                     const float* __restrict__ q_abs,
                                                     const float* __restrict__ qR,
                                                     float* __restrict__ scores) {
  const int b = blockIdx.y;
  const int t0 = blockIdx.x * 8;
  const int tid = threadIdx.x;
  __shared__ float ck[8][512];  // 16 KB
  for (int i = tid; i < 1024; i += 256) {
    int tl = i >> 7, vc = i & 127;
    *(f32x4*)&ck[tl][vc * 4] = *(const f32x4*)(cKV + ((size_t)b * TT + t0 + tl) * 512 + vc * 4);
  }
  __syncthreads();
  const int n = tid & 31, tg = tid >> 5;
  const float* qa = q_abs + ((size_t)(b * 32) + n) * 512;
  float acc = 0.f;
#pragma unroll 8
  for (int vc = 0; vc < 128; ++vc) {
    f32x4 q4 = *(const f32x4*)(qa + vc * 4);
    f32x4 c4 = *(const f32x4*)&ck[tg][vc * 4];
    acc += q4[0] * c4[0] + q4[1] * c4[1] + q4[2] * c4[2] + q4[3] * c4[3];
  }
  const float* qrp = qR + (size_t)b * 2048 + n * 64;
  const float* krp = kR + (((size_t)b * TT + t0 + tg) * 32 + n) * 64;
#pragma unroll
  for (int rc = 0; rc < 16; ++rc) {
    f32x4 q4 = *(const f32x4*)(qrp + rc * 4);
    f32x4 k4 = *(const f32x4*)(krp + rc * 4);
    acc += q4[0] * k4[0] + q4[1] * k4[1] + q4[2] * k4[2] + q4[3] * k4[3];
  }
  scores[((size_t)(b * 32) + n) * T1 + t0 + tg] = acc;
}

// ---------------- cache concat-copy: f32 src[b][T*L] -> f32 dst[b][T1*L] ----------
// idx indexes vec4s; shift = log2(T*L/4); dstStride = T1*L (elements)
__global__ __launch_bounds__(256) void copy_cache(const float* __restrict__ src,
                                                  float* __restrict__ dst,
                                                  int shift, size_t dstStride) {
  size_t idx = (size_t)blockIdx.x * 256 + threadIdx.x;
  const size_t total = (size_t)4 << shift;
  for (; idx < total; idx += (size_t)gridDim.x * 256) {
    int b = (int)(idx >> shift);
    size_t rem = idx & (((size_t)1 << shift) - 1);
    f32x4 v = *(const f32x4*)(src + (idx << 2));
    *(f32x4*)(dst + (size_t)b * dstStride + (rem << 2)) = v;
  }
}

// ---------------- softmax (adds new-token score, mask, scale) ---------------------
// grid 128 (b*32+n); block 256
__global__ __launch_bounds__(256) void softmax_kernel(float* __restrict__ scores,
                                                      const float* __restrict__ mask,
                                                      const float* __restrict__ q_abs,
                                                      const float* __restrict__ cKV_t,
                                                      const float* __restrict__ qR,
                                                      const float* __restrict__ kR_t) {
  const int b = blockIdx.x >> 5, n = blockIdx.x & 31;
  const int tid = threadIdx.x;
  float* srow = scores + ((size_t)(b * 32) + n) * T1;
  const float* qa = q_abs + ((size_t)(b * 32) + n) * 512;
  const float* ck = cKV_t + b * 512;
  float p = qa[tid] * ck[tid] + qa[tid + 256] * ck[tid + 256];
  if (tid < 64) p += qR[(size_t)b * 2048 + n * 64 + tid] * kR_t[(size_t)b * 2048 + n * 64 + tid];
  __shared__ float lds[256];
  lds[tid] = p;
  __syncthreads();
  for (int s = 128; s >= 1; s >>= 1) {
    if (tid < s) lds[tid] += lds[tid + s];
    __syncthreads();
  }
  const float sT = lds[0];
  __syncthreads();
  const float inv_scale = 0.0721687836487032f;  // 1/sqrt(192)
  const float* mrow = mask + ((size_t)(b * 32) + n) * T1;
  float lmax = -1e30f;
  for (int t = tid; t < T1; t += 256) {
    float s0 = (t < TT) ? srow[t] : sT;
    float val = s0 * inv_scale + mrow[t] * (-1e9f);
    srow[t] = val;
    lmax = fmaxf(lmax, val);
  }
  lds[tid] = lmax;
  __syncthreads();
  for (int s = 128; s >= 1; s >>= 1) {
    if (tid < s) lds[tid] = fmaxf(lds[tid], lds[tid + s]);
    __syncthreads();
  }
  const float M = lds[0];
  __syncthreads();
  float lsum = 0.f;
  for (int t = tid; t < T1; t += 256) {
    float e = expf(srow[t] - M);
    srow[t] = e;
    lsum += e;
  }
  lds[tid] = lsum;
  __syncthreads();
  for (int s = 128; s >= 1; s >>= 1) {
    if (tid < s) lds[tid] += lds[tid + s];
    __syncthreads();
  }
  const float inv = 1.0f / lds[0];
  for (int t = tid; t < T1; t += 256) srow[t] *= inv;
}

// ---------------- aggregation partials: aggP[b][chunk][n][v] ----------------------
// grid (NC, 4 b, 4 vh of 128 v); block 256: vg = tid&31 (4 v), ng = tid>>5 (4 n)
__global__ __launch_bounds__(256) void agg_part(const float* __restrict__ cKV,
                                                const float* __restrict__ probs,
                                                float* __restrict__ aggP,
                                                int tlen, int NC) {
  const int chunk = blockIdx.x, b = blockIdx.y, vh = blockIdx.z;
  const int tid = threadIdx.x;
  const int vg = tid & 31, ng = tid >> 5;
  __shared__ float p_lds[32 * 129];
  float acc[4][4];
#pragma unroll
  for (int a = 0; a < 4; ++a)
#pragma unroll
    for (int j = 0; j < 4; ++j) acc[a][j] = 0.f;
  const int sub = (tlen < 128) ? tlen : 128;
  const int sshift = (sub == 64) ? 6 : 7;
  for (int tt = 0; tt < tlen; tt += sub) {
    const int t0 = chunk * tlen + tt;
    __syncthreads();
    for (int i = tid; i < (sub << 5); i += 256) {
      int n = i >> sshift, tl = i & (sub - 1);
      p_lds[n * 129 + tl] = probs[((size_t)(b * 32) + n) * T1 + t0 + tl];
    }
    __syncthreads();
    const float* cbase = cKV + ((size_t)b * TT + t0) * 512 + vh * 128 + vg * 4;
    for (int t = 0; t < sub; t += 2) {
      f32x4 c0 = *(const f32x4*)(cbase + (size_t)t * 512);
      f32x4 c1 = *(const f32x4*)(cbase + (size_t)(t + 1) * 512);
#pragma unroll
      for (int a = 0; a < 4; ++a) {
        float p0 = p_lds[(ng * 4 + a) * 129 + t];
        float p1 = p_lds[(ng * 4 + a) * 129 + t + 1];
#pragma unroll
        for (int j = 0; j < 4; ++j) acc[a][j] += p0 * c0[j] + p1 * c1[j];
      }
    }
  }
#pragma unroll
  for (int a = 0; a < 4; ++a) {
    int n = ng * 4 + a;
    float* dst = aggP + (((size_t)b * NC + chunk) * 32 + n) * 512 + vh * 128 + vg * 4;
    f32x4 v;
#pragma unroll
    for (int j = 0; j < 4; ++j) v[j] = acc[a][j];
    *(f32x4*)dst = v;
  }
}

// ---------------- reduce partials + new-token term -> agg -------------------------
__global__ __launch_bounds__(256) void agg_reduce(const float* __restrict__ aggP,
                                                  const float* __restrict__ probs,
                                                  const float* __restrict__ cKV_t,
                                                  float* __restrict__ agg, int NC) {
  const int idx = blockIdx.x * 256 + threadIdx.x;  // 65536
  const int b = idx >> 14;
  const int n = (idx >> 9) & 31;
  const int v = idx & 511;
  float s = probs[((size_t)(b * 32) + n) * T1 + TT] * cKV_t[b * 512 + v];
  const float* pp = aggP + (((size_t)b * NC) * 32 + n) * 512 + v;
#pragma unroll 4
  for (int c = 0; c < NC; ++c) s += pp[(size_t)c * 32 * 512];
  agg[idx] = s;
}

// ---------------- out1: attn_out[b][n][d] += sum_v agg[b][n][v] * W_UV[v][n][d] ---
// grid (32 n, 8 vc of 64 v); block 256: d = tid&127, bh = tid>>7 (b = bh, bh+2)
__global__ __launch_bounds__(256) void out1_kernel(const float* __restrict__ agg,
                                                   const float* __restrict__ W_UV,
                                                   float* __restrict__ attn_out) {
  const int n = blockIdx.x, vc = blockIdx.y;
  const int tid = threadIdx.x;
  const int d = tid & 127, bh = tid >> 7;
  const float* a0 = agg + ((size_t)(bh * 32) + n) * 512;
  const float* a1 = agg + ((size_t)((bh + 2) * 32) + n) * 512;
  float acc0 = 0.f, acc1 = 0.f;
#pragma unroll 4
  for (int vv = 0; vv < 64; ++vv) {
    int v = vc * 64 + vv;
    float w = W_UV[(size_t)v * 4096 + n * 128 + d];
    acc0 += a0[v] * w;
    acc1 += a1[v] * w;
  }
  atomicAdd(&attn_out[(size_t)bh * 4096 + n * 128 + d], acc0);
  atomicAdd(&attn_out[(size_t)(bh + 2) * 4096 + n * 128 + d], acc1);
}

// ---------------- finalize: f32 output + cache tails ------------------------------
__global__ __launch_bounds__(256) void finalize_kernel(const float* __restrict__ outf,
                                                       const float* __restrict__ cKV_t,
                                                       const float* __restrict__ kR_t,
                                                       float* __restrict__ out) {
  int idx = blockIdx.x * 256 + threadIdx.x;  // 26624 total
  if (idx < 16384) {
    out[idx] = outf[idx];
    return;
  }
  idx -= 16384;
  if (idx < 2048) {
    int b = idx >> 9, v = idx & 511;
    out[16384 + ((size_t)b * T1 + TT) * 512 + v] = cKV_t[idx];
    return;
  }
  idx -= 2048;
  if (idx < 8192) {
    int b = idx >> 11;
    int c = idx & 2047;
    out[16384 + (size_t)8390656 + ((size_t)b * T1 + TT) * 2048 + c] = kR_t[idx];
  }
}

// ---------------- launcher --------------------------------------------------------
extern "C" void kernel_launch(void* const* d_in, const int* in_sizes, int n_in,
                              void* d_out, int out_size, void* d_ws, size_t ws_size,
                              hipStream_t stream) {
  (void)in_sizes; (void)n_in; (void)out_size;
  const float* hidden = (const float*)d_in[0];
  const float* mask   = (const float*)d_in[1];
  const float* cKV    = (const float*)d_in[2];
  const float* kR     = (const float*)d_in[3];
  const float* W_DQ   = (const float*)d_in[4];
  const float* W_DKV  = (const float*)d_in[5];
  const float* W_UQ_C = (const float*)d_in[6];
  const float* W_UQ_R = (const float*)d_in[7];
  const float* W_UK_C = (const float*)d_in[8];
  const float* W_UV_C = (const float*)d_in[9];
  const float* W_KR   = (const float*)d_in[10];
  const float* W_O    = (const float*)d_in[11];

  float* ws = (float*)d_ws;
  // ws layout (float offsets)
  const size_t WS_CQ = 0;           // 6144
  const size_t WS_CKVT = 6144;      // 2048
  const size_t WS_KRT = 8192;       // 8192
  const size_t WS_QC = 16384;       // 16384
  const size_t WS_QR = 32768;       // 8192
  const size_t WS_OUTF = 40960;     // 16384 (atomic target)
  const size_t WS_ATTN = 57344;     // 16384 (atomic target) — zero region [0,73728)
  const size_t WS_AGG = 73728;      // 65536  (written by agg_reduce)
  const size_t WS_QABS = 139264;    // 65536  (written by absorb)
  const size_t WS_SCORES = 204800;  // 524416 (written by scores+softmax)
  const size_t WS_AGGP = 729216;    // NC*65536 floats of partials

  // pick chunk count by available scratch (deterministic per session)
  int NC = 8;
  if (ws_size >= (WS_AGGP + (size_t)64 * 65536) * 4) NC = 64;
  else if (ws_size >= (WS_AGGP + (size_t)32 * 65536) * 4) NC = 32;
  else if (ws_size >= (WS_AGGP + (size_t)16 * 65536) * 4) NC = 16;
  const int tlen = 4096 / NC;

  float* out0 = (float*)d_out;
  float* out_ckv = out0 + 16384;
  float* out_kr = out_ckv + (size_t)8390656;

  hipMemsetAsync(d_ws, 0, 73728 * sizeof(float), stream);

  // projections from hidden (k-split for occupancy)
  gemv_atomic<<<dim3(48, 8), 256, 0, stream>>>(hidden, W_DQ, ws + WS_CQ, 1536, 4096, 512);
  gemv_atomic<<<dim3(16, 16), 256, 0, stream>>>(hidden, W_DKV, ws + WS_CKVT, 512, 4096, 256);
  gemv_atomic<<<dim3(64, 8), 256, 0, stream>>>(hidden, W_KR, ws + WS_KRT, 2048, 4096, 512);
  // q projections from cQ
  gemv_atomic<<<dim3(128, 4), 256, 0, stream>>>(ws + WS_CQ, W_UQ_C, ws + WS_QC, 4096, 1536, 384);
  gemv_atomic<<<dim3(64, 4), 256, 0, stream>>>(ws + WS_CQ, W_UQ_R, ws + WS_QR, 2048, 1536, 384);
  // absorb W_UK into q
  absorb_kernel<<<dim3(32, 4), 128, 0, stream>>>(ws + WS_QC, W_UK_C, ws + WS_QABS);
  // prefix scores (reads cKV + kR from HBM, warms L3)
  scores_kernel<<<dim3(512, 4), 256, 0, stream>>>(cKV, kR, ws + WS_QABS, ws + WS_QR,
                                                  ws + WS_SCORES);
  // softmax
  softmax_kernel<<<128, 256, 0, stream>>>(ws + WS_SCORES, mask, ws + WS_QABS,
                                          ws + WS_CKVT, ws + WS_QR, ws + WS_KRT);
  // p @ cKV aggregation: partials then reduce (+ new-token term)
  agg_part<<<dim3(NC, 4, 4), 256, 0, stream>>>(cKV, ws + WS_SCORES, ws + WS_AGGP,
                                               tlen, NC);
  agg_reduce<<<256, 256, 0, stream>>>(ws + WS_AGGP, ws + WS_SCORES, ws + WS_CKVT,
                                      ws + WS_AGG, NC);
  // apply W_UV then W_O
  out1_kernel<<<dim3(32, 8), 256, 0, stream>>>(ws + WS_AGG, W_UV_C, ws + WS_ATTN);
  gemv_atomic<<<dim3(128, 8), 256, 0, stream>>>(ws + WS_ATTN, W_O, ws + WS_OUTF, 4096, 4096, 512);
  // f32 output + cache tails
  finalize_kernel<<<104, 256, 0, stream>>>(ws + WS_OUTF, ws + WS_CKVT, ws + WS_KRT, out0);
  // cache concat-copies last (read from L3-warm lines, write 168 MB)
  copy_cache<<<2048, 256, 0, stream>>>(cKV, out_ckv, 19, (size_t)T1 * 512);
  copy_cache<<<4096, 256, 0, stream>>>(kR, out_kr, 21, (size_t)T1 * 2048);
}

// Round 7
// 286.511 us; speedup vs baseline: 1.2348x; 1.2348x over previous
//
#include <hip/hip_runtime.h>

#define TT 4096
#define T1 4097

using f32x4 = __attribute__((ext_vector_type(4))) float;

// ---------------- batched GEMV: Y[b][j] += sum_k X[b][k] * W[k][j], all f32 --------
__global__ __launch_bounds__(256) void gemv_atomic(const float* __restrict__ X,
                                                   const float* __restrict__ W,
                                                   float* __restrict__ Y,
                                                   int N, int K, int chunk) {
  const int tid = threadIdx.x;
  const int ct = tid & 7;
  const int kt = tid >> 3;
  const int col0 = blockIdx.x * 32 + ct * 4;
  const int k0 = blockIdx.y * chunk;
  float acc[4][4];
#pragma unroll
  for (int c = 0; c < 4; ++c)
#pragma unroll
    for (int b = 0; b < 4; ++b) acc[c][b] = 0.f;
  const int iters = chunk >> 5;
  for (int i = 0; i < iters; ++i) {
    int k = k0 + kt + (i << 5);
    f32x4 w4 = *(const f32x4*)(W + (size_t)k * N + col0);
    float xb[4];
#pragma unroll
    for (int b = 0; b < 4; ++b) xb[b] = X[(size_t)b * K + k];
#pragma unroll
    for (int c = 0; c < 4; ++c)
#pragma unroll
      for (int b = 0; b < 4; ++b) acc[c][b] += w4[c] * xb[b];
  }
  __shared__ float red[256][16];
#pragma unroll
  for (int c = 0; c < 4; ++c)
#pragma unroll
    for (int b = 0; b < 4; ++b) red[tid][c * 4 + b] = acc[c][b];
  __syncthreads();
  for (int s = 16; s >= 1; s >>= 1) {
    if (kt < s) {
#pragma unroll
      for (int j = 0; j < 16; ++j) red[tid][j] += red[tid + 8 * s][j];
    }
    __syncthreads();
  }
  if (kt == 0) {
#pragma unroll
    for (int c = 0; c < 4; ++c)
#pragma unroll
      for (int b = 0; b < 4; ++b)
        atomicAdd(&Y[(size_t)b * N + col0 + c], red[ct][c * 4 + b]);
  }
}

// ---------------- absorb: q_abs + transposed qT -----------------------------------
// q_abs[b][n][v] and qT[b][v][n] = sum_d qC[b][n][d] * W_UK[v][n][d]
// grid (32 n, 4 vt); block 128: one thread per v
__global__ __launch_bounds__(128) void absorb_kernel(const float* __restrict__ qC,
                                                     const float* __restrict__ W_UK,
                                                     float* __restrict__ q_abs,
                                                     float* __restrict__ qT) {
  const int n = blockIdx.x, vt = blockIdx.y;
  __shared__ float qs[4][128];
  for (int i = threadIdx.x; i < 512; i += 128)
    qs[i >> 7][i & 127] = qC[(size_t)(i >> 7) * 4096 + n * 128 + (i & 127)];
  __syncthreads();
  const int v = vt * 128 + threadIdx.x;
  const float* wp = W_UK + (size_t)v * 4096 + n * 128;
  float acc[4] = {0.f, 0.f, 0.f, 0.f};
#pragma unroll 8
  for (int c = 0; c < 32; ++c) {
    f32x4 w4 = *(const f32x4*)(wp + c * 4);
#pragma unroll
    for (int j = 0; j < 4; ++j)
#pragma unroll
      for (int b = 0; b < 4; ++b) acc[b] += qs[b][c * 4 + j] * w4[j];
  }
#pragma unroll
  for (int b = 0; b < 4; ++b) {
    q_abs[((size_t)(b * 32) + n) * 512 + v] = acc[b];
    qT[((size_t)b * 512 + v) * 32 + n] = acc[b];
  }
}

// ---------------- fused prefix scores + both cache copies -------------------------
// grid (128 t-tiles of 32, 4 b); block 256: tl = tid>>3 (t), ng = tid&7 (4 n each)
__global__ __launch_bounds__(256) void scores_fused(const float* __restrict__ cKV,
                                                    const float* __restrict__ kR,
                                                    const float* __restrict__ qT,
                                                    const float* __restrict__ qR,
                                                    float* __restrict__ scores,
                                                    float* __restrict__ out_ckv,
                                                    float* __restrict__ out_kr) {
  const int b = blockIdx.y;
  const int t0 = blockIdx.x * 32;
  const int tid = threadIdx.x;
  __shared__ float ck[32][516];  // padded: 66 KB, 2 blocks/CU
  // Phase A: stage cKV tile (32 x 512) + pass-through copy
  for (int i = tid; i < 4096; i += 256) {
    int tl_ = i >> 7, vc = i & 127;
    f32x4 v = *(const f32x4*)(cKV + ((size_t)b * TT + t0 + tl_) * 512 + vc * 4);
    *(f32x4*)&ck[tl_][vc * 4] = v;
    *(f32x4*)(out_ckv + ((size_t)b * T1 + t0 + tl_) * 512 + vc * 4) = v;
  }
  // Phase C: kR tile copy (coalesced stream; warms L2 for Phase B)
  for (int i = tid; i < 16384; i += 256) {
    int tl_ = i >> 9, c = i & 511;
    f32x4 v = *(const f32x4*)(kR + ((size_t)b * TT + t0 + tl_) * 2048 + c * 4);
    *(f32x4*)(out_kr + ((size_t)b * T1 + t0 + tl_) * 2048 + c * 4) = v;
  }
  __syncthreads();
  // Phase QK: acc[j] = sum_v qT[b][v][ng*4+j] * ck[tl][v]
  const int tl = tid >> 3, ng = tid & 7;
  const float* qtb = qT + (size_t)b * 512 * 32 + ng * 4;
  float a0 = 0.f, a1 = 0.f, a2 = 0.f, a3 = 0.f;
#pragma unroll 4
  for (int vc2 = 0; vc2 < 256; ++vc2) {
    float c0 = ck[tl][vc2 * 2];
    float c1 = ck[tl][vc2 * 2 + 1];
    f32x4 qa = *(const f32x4*)(qtb + (size_t)(vc2 * 2) * 32);
    f32x4 qb = *(const f32x4*)(qtb + (size_t)(vc2 * 2 + 1) * 32);
    a0 += qa[0] * c0 + qb[0] * c1;
    a1 += qa[1] * c0 + qb[1] * c1;
    a2 += qa[2] * c0 + qb[2] * c1;
    a3 += qa[3] * c0 + qb[3] * c1;
  }
  float acc[4] = {a0, a1, a2, a3};
  // Phase B: kR dot (rows L2-warm from Phase C)
  const int t = t0 + tl;
  const float* krb = kR + ((size_t)b * TT + t) * 2048;
  const float* qrb = qR + (size_t)b * 2048;
#pragma unroll
  for (int j = 0; j < 4; ++j) {
    const int n = ng * 4 + j;
    float s = 0.f;
#pragma unroll
    for (int rc = 0; rc < 16; ++rc) {
      f32x4 k4 = *(const f32x4*)(krb + n * 64 + rc * 4);
      f32x4 q4 = *(const f32x4*)(qrb + n * 64 + rc * 4);
      s += k4[0] * q4[0] + k4[1] * q4[1] + k4[2] * q4[2] + k4[3] * q4[3];
    }
    scores[((size_t)(b * 32) + n) * T1 + t] = acc[j] + s;
  }
}

// ---------------- softmax (adds new-token score, mask, scale) ---------------------
// grid 128 (b*32+n); block 256
__global__ __launch_bounds__(256) void softmax_kernel(float* __restrict__ scores,
                                                      const float* __restrict__ mask,
                                                      const float* __restrict__ q_abs,
                                                      const float* __restrict__ cKV_t,
                                                      const float* __restrict__ qR,
                                                      const float* __restrict__ kR_t) {
  const int b = blockIdx.x >> 5, n = blockIdx.x & 31;
  const int tid = threadIdx.x;
  float* srow = scores + ((size_t)(b * 32) + n) * T1;
  const float* qa = q_abs + ((size_t)(b * 32) + n) * 512;
  const float* ck = cKV_t + b * 512;
  float p = qa[tid] * ck[tid] + qa[tid + 256] * ck[tid + 256];
  if (tid < 64) p += qR[(size_t)b * 2048 + n * 64 + tid] * kR_t[(size_t)b * 2048 + n * 64 + tid];
  __shared__ float lds[256];
  lds[tid] = p;
  __syncthreads();
  for (int s = 128; s >= 1; s >>= 1) {
    if (tid < s) lds[tid] += lds[tid + s];
    __syncthreads();
  }
  const float sT = lds[0];
  __syncthreads();
  const float inv_scale = 0.0721687836487032f;  // 1/sqrt(192)
  const float* mrow = mask + ((size_t)(b * 32) + n) * T1;
  float lmax = -1e30f;
  for (int t = tid; t < T1; t += 256) {
    float s0 = (t < TT) ? srow[t] : sT;
    float val = s0 * inv_scale + mrow[t] * (-1e9f);
    srow[t] = val;
    lmax = fmaxf(lmax, val);
  }
  lds[tid] = lmax;
  __syncthreads();
  for (int s = 128; s >= 1; s >>= 1) {
    if (tid < s) lds[tid] = fmaxf(lds[tid], lds[tid + s]);
    __syncthreads();
  }
  const float M = lds[0];
  __syncthreads();
  float lsum = 0.f;
  for (int t = tid; t < T1; t += 256) {
    float e = expf(srow[t] - M);
    srow[t] = e;
    lsum += e;
  }
  lds[tid] = lsum;
  __syncthreads();
  for (int s = 128; s >= 1; s >>= 1) {
    if (tid < s) lds[tid] += lds[tid + s];
    __syncthreads();
  }
  const float inv = 1.0f / lds[0];
  for (int t = tid; t < T1; t += 256) srow[t] *= inv;
}

// ---------------- aggregation partials: aggP[b][chunk][n][v] ----------------------
// grid (NC, 4 b, 4 vh of 128 v); block 256: vg = tid&31 (4 v), ng = tid>>5 (4 n)
__global__ __launch_bounds__(256) void agg_part(const float* __restrict__ cKV,
                                                const float* __restrict__ probs,
                                                float* __restrict__ aggP,
                                                int tlen, int NC) {
  const int chunk = blockIdx.x, b = blockIdx.y, vh = blockIdx.z;
  const int tid = threadIdx.x;
  const int vg = tid & 31, ng = tid >> 5;
  __shared__ float p_lds[32 * 129];
  float acc[4][4];
#pragma unroll
  for (int a = 0; a < 4; ++a)
#pragma unroll
    for (int j = 0; j < 4; ++j) acc[a][j] = 0.f;
  const int sub = (tlen < 128) ? tlen : 128;
  const int sshift = (sub == 64) ? 6 : 7;
  for (int tt = 0; tt < tlen; tt += sub) {
    const int t0 = chunk * tlen + tt;
    __syncthreads();
    for (int i = tid; i < (sub << 5); i += 256) {
      int n = i >> sshift, tl = i & (sub - 1);
      p_lds[n * 129 + tl] = probs[((size_t)(b * 32) + n) * T1 + t0 + tl];
    }
    __syncthreads();
    const float* cbase = cKV + ((size_t)b * TT + t0) * 512 + vh * 128 + vg * 4;
    for (int t = 0; t < sub; t += 2) {
      f32x4 c0 = *(const f32x4*)(cbase + (size_t)t * 512);
      f32x4 c1 = *(const f32x4*)(cbase + (size_t)(t + 1) * 512);
#pragma unroll
      for (int a = 0; a < 4; ++a) {
        float p0 = p_lds[(ng * 4 + a) * 129 + t];
        float p1 = p_lds[(ng * 4 + a) * 129 + t + 1];
#pragma unroll
        for (int j = 0; j < 4; ++j) acc[a][j] += p0 * c0[j] + p1 * c1[j];
      }
    }
  }
#pragma unroll
  for (int a = 0; a < 4; ++a) {
    int n = ng * 4 + a;
    float* dst = aggP + (((size_t)b * NC + chunk) * 32 + n) * 512 + vh * 128 + vg * 4;
    f32x4 v;
#pragma unroll
    for (int j = 0; j < 4; ++j) v[j] = acc[a][j];
    *(f32x4*)dst = v;
  }
}

// ---------------- reduce partials + new-token term -> agg -------------------------
__global__ __launch_bounds__(256) void agg_reduce(const float* __restrict__ aggP,
                                                  const float* __restrict__ probs,
                                                  const float* __restrict__ cKV_t,
                                                  float* __restrict__ agg, int NC) {
  const int idx = blockIdx.x * 256 + threadIdx.x;  // 65536
  const int b = idx >> 14;
  const int n = (idx >> 9) & 31;
  const int v = idx & 511;
  float s = probs[((size_t)(b * 32) + n) * T1 + TT] * cKV_t[b * 512 + v];
  const float* pp = aggP + (((size_t)b * NC) * 32 + n) * 512 + v;
#pragma unroll 4
  for (int c = 0; c < NC; ++c) s += pp[(size_t)c * 32 * 512];
  agg[idx] = s;
}

// ---------------- out1: attn_out[b][n][d] += sum_v agg[b][n][v] * W_UV[v][n][d] ---
// grid (32 n, 8 vc of 64 v); block 256: d = tid&127, bh = tid>>7 (b = bh, bh+2)
__global__ __launch_bounds__(256) void out1_kernel(const float* __restrict__ agg,
                                                   const float* __restrict__ W_UV,
                                                   float* __restrict__ attn_out) {
  const int n = blockIdx.x, vc = blockIdx.y;
  const int tid = threadIdx.x;
  const int d = tid & 127, bh = tid >> 7;
  const float* a0 = agg + ((size_t)(bh * 32) + n) * 512;
  const float* a1 = agg + ((size_t)((bh + 2) * 32) + n) * 512;
  float acc0 = 0.f, acc1 = 0.f;
#pragma unroll 4
  for (int vv = 0; vv < 64; ++vv) {
    int v = vc * 64 + vv;
    float w = W_UV[(size_t)v * 4096 + n * 128 + d];
    acc0 += a0[v] * w;
    acc1 += a1[v] * w;
  }
  atomicAdd(&attn_out[(size_t)bh * 4096 + n * 128 + d], acc0);
  atomicAdd(&attn_out[(size_t)(bh + 2) * 4096 + n * 128 + d], acc1);
}

// ---------------- finalize: f32 output + cache tails ------------------------------
__global__ __launch_bounds__(256) void finalize_kernel(const float* __restrict__ outf,
                                                       const float* __restrict__ cKV_t,
                                                       const float* __restrict__ kR_t,
                                                       float* __restrict__ out) {
  int idx = blockIdx.x * 256 + threadIdx.x;  // 26624 total
  if (idx < 16384) {
    out[idx] = outf[idx];
    return;
  }
  idx -= 16384;
  if (idx < 2048) {
    int b = idx >> 9, v = idx & 511;
    out[16384 + ((size_t)b * T1 + TT) * 512 + v] = cKV_t[idx];
    return;
  }
  idx -= 2048;
  if (idx < 8192) {
    int b = idx >> 11;
    int c = idx & 2047;
    out[16384 + (size_t)8390656 + ((size_t)b * T1 + TT) * 2048 + c] = kR_t[idx];
  }
}

// ---------------- launcher --------------------------------------------------------
extern "C" void kernel_launch(void* const* d_in, const int* in_sizes, int n_in,
                              void* d_out, int out_size, void* d_ws, size_t ws_size,
                              hipStream_t stream) {
  (void)in_sizes; (void)n_in; (void)out_size;
  const float* hidden = (const float*)d_in[0];
  const float* mask   = (const float*)d_in[1];
  const float* cKV    = (const float*)d_in[2];
  const float* kR     = (const float*)d_in[3];
  const float* W_DQ   = (const float*)d_in[4];
  const float* W_DKV  = (const float*)d_in[5];
  const float* W_UQ_C = (const float*)d_in[6];
  const float* W_UQ_R = (const float*)d_in[7];
  const float* W_UK_C = (const float*)d_in[8];
  const float* W_UV_C = (const float*)d_in[9];
  const float* W_KR   = (const float*)d_in[10];
  const float* W_O    = (const float*)d_in[11];

  float* ws = (float*)d_ws;
  // ws layout (float offsets)
  const size_t WS_CQ = 0;           // 6144
  const size_t WS_CKVT = 6144;      // 2048
  const size_t WS_KRT = 8192;       // 8192
  const size_t WS_QC = 16384;       // 16384
  const size_t WS_QR = 32768;       // 8192
  const size_t WS_OUTF = 40960;     // 16384 (atomic target)
  const size_t WS_ATTN = 57344;     // 16384 (atomic target) — zero region [0,73728)
  const size_t WS_AGG = 73728;      // 65536  (written by agg_reduce)
  const size_t WS_QABS = 139264;    // 65536  (written by absorb)
  const size_t WS_SCORES = 204800;  // 524416 (written by scores+softmax)
  const size_t WS_QT = 729216;      // 65536  (written by absorb, transposed)
  const size_t WS_AGGP = 794752;    // NC*65536 floats of partials

  // pick chunk count by available scratch (deterministic per session)
  int NC = 8;
  if (ws_size >= (WS_AGGP + (size_t)64 * 65536) * 4) NC = 64;
  else if (ws_size >= (WS_AGGP + (size_t)32 * 65536) * 4) NC = 32;
  else if (ws_size >= (WS_AGGP + (size_t)16 * 65536) * 4) NC = 16;
  const int tlen = 4096 / NC;

  float* out0 = (float*)d_out;
  float* out_ckv = out0 + 16384;
  float* out_kr = out_ckv + (size_t)8390656;

  hipMemsetAsync(d_ws, 0, 73728 * sizeof(float), stream);

  // projections from hidden (k-split for occupancy)
  gemv_atomic<<<dim3(48, 8), 256, 0, stream>>>(hidden, W_DQ, ws + WS_CQ, 1536, 4096, 512);
  gemv_atomic<<<dim3(16, 16), 256, 0, stream>>>(hidden, W_DKV, ws + WS_CKVT, 512, 4096, 256);
  gemv_atomic<<<dim3(64, 8), 256, 0, stream>>>(hidden, W_KR, ws + WS_KRT, 2048, 4096, 512);
  // q projections from cQ
  gemv_atomic<<<dim3(128, 4), 256, 0, stream>>>(ws + WS_CQ, W_UQ_C, ws + WS_QC, 4096, 1536, 384);
  gemv_atomic<<<dim3(64, 4), 256, 0, stream>>>(ws + WS_CQ, W_UQ_R, ws + WS_QR, 2048, 1536, 384);
  // absorb W_UK into q (both layouts)
  absorb_kernel<<<dim3(32, 4), 128, 0, stream>>>(ws + WS_QC, W_UK_C, ws + WS_QABS, ws + WS_QT);
  // fused prefix scores + both cache copies
  scores_fused<<<dim3(128, 4), 256, 0, stream>>>(cKV, kR, ws + WS_QT, ws + WS_QR,
                                                 ws + WS_SCORES, out_ckv, out_kr);
  // softmax
  softmax_kernel<<<128, 256, 0, stream>>>(ws + WS_SCORES, mask, ws + WS_QABS,
                                          ws + WS_CKVT, ws + WS_QR, ws + WS_KRT);
  // p @ cKV aggregation: partials then reduce (+ new-token term)
  agg_part<<<dim3(NC, 4, 4), 256, 0, stream>>>(cKV, ws + WS_SCORES, ws + WS_AGGP,
                                               tlen, NC);
  agg_reduce<<<256, 256, 0, stream>>>(ws + WS_AGGP, ws + WS_SCORES, ws + WS_CKVT,
                                      ws + WS_AGG, NC);
  // apply W_UV then W_O
  out1_kernel<<<dim3(32, 8), 256, 0, stream>>>(ws + WS_AGG, W_UV_C, ws + WS_ATTN);
  gemv_atomic<<<dim3(128, 8), 256, 0, stream>>>(ws + WS_ATTN, W_O, ws + WS_OUTF, 4096, 4096, 512);
  // f32 output + cache tails
  finalize_kernel<<<104, 256, 0, stream>>>(ws + WS_OUTF, ws + WS_CKVT, ws + WS_KRT, out0);
}

// Round 8
// 256.069 us; speedup vs baseline: 1.3816x; 1.1189x over previous
//
#include <hip/hip_runtime.h>

#define TT 4096
#define T1 4097

using f32x4 = __attribute__((ext_vector_type(4))) float;
using f32x2 = __attribute__((ext_vector_type(2))) float;

// ---------------- shared GEMV body: Y[b][j] += sum_k X[b][k] * W[k][j] ------------
__device__ __forceinline__ void gemv_body(const float* __restrict__ X,
                                          const float* __restrict__ W,
                                          float* __restrict__ Y,
                                          int N, int K, int chunk, int ky) {
  const int tid = threadIdx.x;
  const int ct = tid & 7;
  const int kt = tid >> 3;
  const int col0 = blockIdx.x * 32 + ct * 4;
  const int k0 = ky * chunk;
  float acc[4][4];
#pragma unroll
  for (int c = 0; c < 4; ++c)
#pragma unroll
    for (int b = 0; b < 4; ++b) acc[c][b] = 0.f;
  const int iters = chunk >> 5;
  for (int i = 0; i < iters; ++i) {
    int k = k0 + kt + (i << 5);
    f32x4 w4 = *(const f32x4*)(W + (size_t)k * N + col0);
    float xb[4];
#pragma unroll
    for (int b = 0; b < 4; ++b) xb[b] = X[(size_t)b * K + k];
#pragma unroll
    for (int c = 0; c < 4; ++c)
#pragma unroll
      for (int b = 0; b < 4; ++b) acc[c][b] += w4[c] * xb[b];
  }
  __shared__ float red[256][16];
#pragma unroll
  for (int c = 0; c < 4; ++c)
#pragma unroll
    for (int b = 0; b < 4; ++b) red[tid][c * 4 + b] = acc[c][b];
  __syncthreads();
  for (int s = 16; s >= 1; s >>= 1) {
    if (kt < s) {
#pragma unroll
      for (int j = 0; j < 16; ++j) red[tid][j] += red[tid + 8 * s][j];
    }
    __syncthreads();
  }
  if (kt == 0) {
#pragma unroll
    for (int c = 0; c < 4; ++c)
#pragma unroll
      for (int b = 0; b < 4; ++b)
        atomicAdd(&Y[(size_t)b * N + col0 + c], red[ct][c * 4 + b]);
  }
}

// ---------------- hidden projections: W_DQ / W_DKV / W_KR in one launch -----------
// grid (64, 8, 3); K = 4096, chunk = 512
__global__ __launch_bounds__(256) void gemv_hidden(const float* __restrict__ X,
                                                   const float* __restrict__ W0,
                                                   const float* __restrict__ W1,
                                                   const float* __restrict__ W2,
                                                   float* __restrict__ Ybase) {
  const int z = blockIdx.z;
  const float* W = (z == 0) ? W0 : (z == 1) ? W1 : W2;
  const int N = (z == 0) ? 1536 : (z == 1) ? 512 : 2048;
  const int nb = (z == 0) ? 48 : (z == 1) ? 16 : 64;
  const size_t yoff = (z == 0) ? 0 : (z == 1) ? 6144 : 8192;
  if ((int)blockIdx.x >= nb) return;
  gemv_body(X, W, Ybase + yoff, N, 4096, 512, blockIdx.y);
}

// ---------------- cQ projections: W_UQ_C / W_UQ_R in one launch -------------------
// grid (128, 4, 2); K = 1536, chunk = 384
__global__ __launch_bounds__(256) void gemv_cq(const float* __restrict__ X,
                                               const float* __restrict__ W0,
                                               const float* __restrict__ W1,
                                               float* __restrict__ Y0,
                                               float* __restrict__ Y1) {
  const int z = blockIdx.z;
  const float* W = (z == 0) ? W0 : W1;
  float* Y = (z == 0) ? Y0 : Y1;
  const int N = (z == 0) ? 4096 : 2048;
  const int nb = (z == 0) ? 128 : 64;
  if ((int)blockIdx.x >= nb) return;
  gemv_body(X, W, Y, N, 1536, 384, blockIdx.y);
}

// ---------------- gemv for W_O ----------------------------------------------------
__global__ __launch_bounds__(256) void gemv_atomic(const float* __restrict__ X,
                                                   const float* __restrict__ W,
                                                   float* __restrict__ Y,
                                                   int N, int K, int chunk) {
  gemv_body(X, W, Y, N, K, chunk, blockIdx.y);
}

// ---------------- absorb: q_abs + transposed qT -----------------------------------
// grid (32 n, 4 vt); block 128: one thread per v
__global__ __launch_bounds__(128) void absorb_kernel(const float* __restrict__ qC,
                                                     const float* __restrict__ W_UK,
                                                     float* __restrict__ q_abs,
                                                     float* __restrict__ qT) {
  const int n = blockIdx.x, vt = blockIdx.y;
  __shared__ float qs[4][128];
  for (int i = threadIdx.x; i < 512; i += 128)
    qs[i >> 7][i & 127] = qC[(size_t)(i >> 7) * 4096 + n * 128 + (i & 127)];
  __syncthreads();
  const int v = vt * 128 + threadIdx.x;
  const float* wp = W_UK + (size_t)v * 4096 + n * 128;
  float acc[4] = {0.f, 0.f, 0.f, 0.f};
#pragma unroll 8
  for (int c = 0; c < 32; ++c) {
    f32x4 w4 = *(const f32x4*)(wp + c * 4);
#pragma unroll
    for (int j = 0; j < 4; ++j)
#pragma unroll
      for (int b = 0; b < 4; ++b) acc[b] += qs[b][c * 4 + j] * w4[j];
  }
#pragma unroll
  for (int b = 0; b < 4; ++b) {
    q_abs[((size_t)(b * 32) + n) * 512 + v] = acc[b];
    qT[((size_t)b * 512 + v) * 32 + n] = acc[b];
  }
}

// ---------------- combined scores + both cache copies (block-specialized) ---------
// grid 2560: bid%5==4 -> kR-stream block (512: 128 t-tiles of 32 x 4 b)
//            else     -> cKV block       (2048: 512 t-tiles of 8 x 4 b)
__global__ __launch_bounds__(256) void scores_combined(const float* __restrict__ cKV,
                                                       const float* __restrict__ kR,
                                                       const float* __restrict__ qT,
                                                       const float* __restrict__ qR,
                                                       float* __restrict__ scores,
                                                       float* __restrict__ scoresR,
                                                       float* __restrict__ out_ckv,
                                                       float* __restrict__ out_kr) {
  const int bid = blockIdx.x;
  const int tid = threadIdx.x;
  __shared__ float ck[8][516];  // 16.5 KB
  if ((bid % 5) != 4) {
    // ---- cKV block: stage 8x512 tile, write-through copy, QK dot from LDS ----
    const int cidx = (bid / 5) * 4 + (bid % 5);
    const int b = cidx & 3;
    const int t0 = (cidx >> 2) * 8;
    for (int i = tid; i < 1024; i += 256) {
      int tl = i >> 7, vc = i & 127;
      f32x4 v = *(const f32x4*)(cKV + ((size_t)b * TT + t0 + tl) * 512 + vc * 4);
      *(f32x4*)&ck[tl][vc * 4] = v;
      *(f32x4*)(out_ckv + ((size_t)b * T1 + t0 + tl) * 512 + vc * 4) = v;
    }
    __syncthreads();
    const int tl = tid >> 5, ng = tid & 31;
    const float* qtb = qT + (size_t)b * 16384 + ng;
    float a0 = 0.f;
#pragma unroll 8
    for (int v = 0; v < 512; ++v) a0 += qtb[(size_t)v * 32] * ck[tl][v];
    scores[((size_t)(b * 32) + ng) * T1 + t0 + tl] = a0;
  } else {
    // ---- kR block: stream-copy 32x2048 tile + rope-score dot ----
    const int kidx = bid / 5;
    const int b = kidx & 3;
    const int t0 = (kidx >> 2) * 32;
    const float* qrb = qR + (size_t)b * 2048;
    for (int k = 0; k < 64; ++k) {
      const int i = tid + (k << 8);
      const int tl = i >> 9, c = i & 511;
      const int t = t0 + tl;
      f32x4 v = *(const f32x4*)(kR + ((size_t)b * TT + t) * 2048 + c * 4);
      *(f32x4*)(out_kr + ((size_t)b * T1 + t) * 2048 + c * 4) = v;
      const int n = c >> 4;
      const int r4 = (c & 15) * 4;
      f32x4 q4 = *(const f32x4*)(qrb + n * 64 + r4);
      float p = v[0] * q4[0] + v[1] * q4[1] + v[2] * q4[2] + v[3] * q4[3];
      p += __shfl_xor(p, 1);
      p += __shfl_xor(p, 2);
      p += __shfl_xor(p, 4);
      p += __shfl_xor(p, 8);
      if ((tid & 15) == 0) scoresR[((size_t)(b * 32) + n) * T1 + t] = p;
    }
  }
}

// ---------------- softmax (adds scoresR + new-token score, mask, scale) -----------
// grid 128 (b*32+n); block 256
__global__ __launch_bounds__(256) void softmax_kernel(float* __restrict__ scores,
                                                      const float* __restrict__ scoresR,
                                                      const float* __restrict__ mask,
                                                      const float* __restrict__ q_abs,
                                                      const float* __restrict__ cKV_t,
                                                      const float* __restrict__ qR,
                                                      const float* __restrict__ kR_t) {
  const int b = blockIdx.x >> 5, n = blockIdx.x & 31;
  const int tid = threadIdx.x;
  float* srow = scores + ((size_t)(b * 32) + n) * T1;
  const float* scrow = scoresR + ((size_t)(b * 32) + n) * T1;
  const float* qa = q_abs + ((size_t)(b * 32) + n) * 512;
  const float* ck = cKV_t + b * 512;
  float p = qa[tid] * ck[tid] + qa[tid + 256] * ck[tid + 256];
  if (tid < 64) p += qR[(size_t)b * 2048 + n * 64 + tid] * kR_t[(size_t)b * 2048 + n * 64 + tid];
  __shared__ float lds[256];
  lds[tid] = p;
  __syncthreads();
  for (int s = 128; s >= 1; s >>= 1) {
    if (tid < s) lds[tid] += lds[tid + s];
    __syncthreads();
  }
  const float sT = lds[0];
  __syncthreads();
  const float inv_scale = 0.0721687836487032f;  // 1/sqrt(192)
  const float* mrow = mask + ((size_t)(b * 32) + n) * T1;
  float lmax = -1e30f;
  for (int t = tid; t < T1; t += 256) {
    float s0 = (t < TT) ? (srow[t] + scrow[t]) : sT;
    float val = s0 * inv_scale + mrow[t] * (-1e9f);
    srow[t] = val;
    lmax = fmaxf(lmax, val);
  }
  lds[tid] = lmax;
  __syncthreads();
  for (int s = 128; s >= 1; s >>= 1) {
    if (tid < s) lds[tid] = fmaxf(lds[tid], lds[tid + s]);
    __syncthreads();
  }
  const float M = lds[0];
  __syncthreads();
  float lsum = 0.f;
  for (int t = tid; t < T1; t += 256) {
    float e = expf(srow[t] - M);
    srow[t] = e;
    lsum += e;
  }
  lds[tid] = lsum;
  __syncthreads();
  for (int s = 128; s >= 1; s >>= 1) {
    if (tid < s) lds[tid] += lds[tid + s];
    __syncthreads();
  }
  const float inv = 1.0f / lds[0];
  for (int t = tid; t < T1; t += 256) srow[t] *= inv;
}

// ---------------- aggregation partials: aggP[b][chunk][n][v] ----------------------
// grid (NC, 4 b, 4 vh of 128 v); block 256: vg = tid&31 (4 v), ng = tid>>5 (4 n)
__global__ __launch_bounds__(256) void agg_part(const float* __restrict__ cKV,
                                                const float* __restrict__ probs,
                                                float* __restrict__ aggP,
                                                int tlen, int NC) {
  const int chunk = blockIdx.x, b = blockIdx.y, vh = blockIdx.z;
  const int tid = threadIdx.x;
  const int vg = tid & 31, ng = tid >> 5;
  __shared__ float p_lds[32 * 129];
  float acc[4][4];
#pragma unroll
  for (int a = 0; a < 4; ++a)
#pragma unroll
    for (int j = 0; j < 4; ++j) acc[a][j] = 0.f;
  const int sub = (tlen < 128) ? tlen : 128;
  const int sshift = (sub == 64) ? 6 : 7;
  for (int tt = 0; tt < tlen; tt += sub) {
    const int t0 = chunk * tlen + tt;
    __syncthreads();
    for (int i = tid; i < (sub << 5); i += 256) {
      int n = i >> sshift, tl = i & (sub - 1);
      p_lds[n * 129 + tl] = probs[((size_t)(b * 32) + n) * T1 + t0 + tl];
    }
    __syncthreads();
    const float* cbase = cKV + ((size_t)b * TT + t0) * 512 + vh * 128 + vg * 4;
    for (int t = 0; t < sub; t += 2) {
      f32x4 c0 = *(const f32x4*)(cbase + (size_t)t * 512);
      f32x4 c1 = *(const f32x4*)(cbase + (size_t)(t + 1) * 512);
#pragma unroll
      for (int a = 0; a < 4; ++a) {
        float p0 = p_lds[(ng * 4 + a) * 129 + t];
        float p1 = p_lds[(ng * 4 + a) * 129 + t + 1];
#pragma unroll
        for (int j = 0; j < 4; ++j) acc[a][j] += p0 * c0[j] + p1 * c1[j];
      }
    }
  }
#pragma unroll
  for (int a = 0; a < 4; ++a) {
    int n = ng * 4 + a;
    float* dst = aggP + (((size_t)b * NC + chunk) * 32 + n) * 512 + vh * 128 + vg * 4;
    f32x4 v;
#pragma unroll
    for (int j = 0; j < 4; ++j) v[j] = acc[a][j];
    *(f32x4*)dst = v;
  }
}

// ---------------- reduce partials + new-token term -> agg -------------------------
__global__ __launch_bounds__(256) void agg_reduce(const float* __restrict__ aggP,
                                                  const float* __restrict__ probs,
                                                  const float* __restrict__ cKV_t,
                                                  float* __restrict__ agg, int NC) {
  const int idx = blockIdx.x * 256 + threadIdx.x;  // 65536
  const int b = idx >> 14;
  const int n = (idx >> 9) & 31;
  const int v = idx & 511;
  float s = probs[((size_t)(b * 32) + n) * T1 + TT] * cKV_t[b * 512 + v];
  const float* pp = aggP + (((size_t)b * NC) * 32 + n) * 512 + v;
#pragma unroll 4
  for (int c = 0; c < NC; ++c) s += pp[(size_t)c * 32 * 512];
  agg[idx] = s;
}

// ---------------- out1: attn_out[b][n][d] += sum_v agg[b][n][v] * W_UV[v][n][d] ---
// grid (32 n, 8 vc of 64 v); block 256: d = tid&127, bh = tid>>7 (b = bh, bh+2)
__global__ __launch_bounds__(256) void out1_kernel(const float* __restrict__ agg,
                                                   const float* __restrict__ W_UV,
                                                   float* __restrict__ attn_out) {
  const int n = blockIdx.x, vc = blockIdx.y;
  const int tid = threadIdx.x;
  const int d = tid & 127, bh = tid >> 7;
  const float* a0 = agg + ((size_t)(bh * 32) + n) * 512;
  const float* a1 = agg + ((size_t)((bh + 2) * 32) + n) * 512;
  float acc0 = 0.f, acc1 = 0.f;
#pragma unroll 4
  for (int vv = 0; vv < 64; ++vv) {
    int v = vc * 64 + vv;
    float w = W_UV[(size_t)v * 4096 + n * 128 + d];
    acc0 += a0[v] * w;
    acc1 += a1[v] * w;
  }
  atomicAdd(&attn_out[(size_t)bh * 4096 + n * 128 + d], acc0);
  atomicAdd(&attn_out[(size_t)(bh + 2) * 4096 + n * 128 + d], acc1);
}

// ---------------- finalize: f32 output + cache tails ------------------------------
__global__ __launch_bounds__(256) void finalize_kernel(const float* __restrict__ outf,
                                                       const float* __restrict__ cKV_t,
                                                       const float* __restrict__ kR_t,
                                                       float* __restrict__ out) {
  int idx = blockIdx.x * 256 + threadIdx.x;  // 26624 total
  if (idx < 16384) {
    out[idx] = outf[idx];
    return;
  }
  idx -= 16384;
  if (idx < 2048) {
    int b = idx >> 9, v = idx & 511;
    out[16384 + ((size_t)b * T1 + TT) * 512 + v] = cKV_t[idx];
    return;
  }
  idx -= 2048;
  if (idx < 8192) {
    int b = idx >> 11;
    int c = idx & 2047;
    out[16384 + (size_t)8390656 + ((size_t)b * T1 + TT) * 2048 + c] = kR_t[idx];
  }
}

// ---------------- launcher --------------------------------------------------------
extern "C" void kernel_launch(void* const* d_in, const int* in_sizes, int n_in,
                              void* d_out, int out_size, void* d_ws, size_t ws_size,
                              hipStream_t stream) {
  (void)in_sizes; (void)n_in; (void)out_size;
  const float* hidden = (const float*)d_in[0];
  const float* mask   = (const float*)d_in[1];
  const float* cKV    = (const float*)d_in[2];
  const float* kR     = (const float*)d_in[3];
  const float* W_DQ   = (const float*)d_in[4];
  const float* W_DKV  = (const float*)d_in[5];
  const float* W_UQ_C = (const float*)d_in[6];
  const float* W_UQ_R = (const float*)d_in[7];
  const float* W_UK_C = (const float*)d_in[8];
  const float* W_UV_C = (const float*)d_in[9];
  const float* W_KR   = (const float*)d_in[10];
  const float* W_O    = (const float*)d_in[11];

  float* ws = (float*)d_ws;
  // ws layout (float offsets)
  const size_t WS_CQ = 0;           // 6144
  const size_t WS_CKVT = 6144;      // 2048
  const size_t WS_KRT = 8192;       // 8192
  const size_t WS_QC = 16384;       // 16384
  const size_t WS_QR = 32768;       // 8192
  const size_t WS_OUTF = 40960;     // 16384 (atomic target)
  const size_t WS_ATTN = 57344;     // 16384 (atomic target) — zero region [0,73728)
  const size_t WS_AGG = 73728;      // 65536
  const size_t WS_QABS = 139264;    // 65536
  const size_t WS_SCORES = 204800;  // 524416
  const size_t WS_QT = 729216;      // 65536
  const size_t WS_SCR = 794752;     // 524416 (rope partial scores)
  const size_t WS_AGGP = 1319168;   // NC*65536 floats of partials

  // pick chunk count by available scratch (deterministic per session)
  int NC = 8;
  if (ws_size >= (WS_AGGP + (size_t)64 * 65536) * 4) NC = 64;
  else if (ws_size >= (WS_AGGP + (size_t)32 * 65536) * 4) NC = 32;
  else if (ws_size >= (WS_AGGP + (size_t)16 * 65536) * 4) NC = 16;
  const int tlen = 4096 / NC;

  float* out0 = (float*)d_out;
  float* out_ckv = out0 + 16384;
  float* out_kr = out_ckv + (size_t)8390656;

  hipMemsetAsync(d_ws, 0, 73728 * sizeof(float), stream);

  // projections from hidden (3-in-1)
  gemv_hidden<<<dim3(64, 8, 3), 256, 0, stream>>>(hidden, W_DQ, W_DKV, W_KR, ws);
  // q projections from cQ (2-in-1)
  gemv_cq<<<dim3(128, 4, 2), 256, 0, stream>>>(ws + WS_CQ, W_UQ_C, W_UQ_R,
                                               ws + WS_QC, ws + WS_QR);
  // absorb W_UK into q (both layouts)
  absorb_kernel<<<dim3(32, 4), 128, 0, stream>>>(ws + WS_QC, W_UK_C, ws + WS_QABS, ws + WS_QT);
  // combined scores + both cache copies (block-specialized)
  scores_combined<<<2560, 256, 0, stream>>>(cKV, kR, ws + WS_QT, ws + WS_QR,
                                            ws + WS_SCORES, ws + WS_SCR, out_ckv, out_kr);
  // softmax
  softmax_kernel<<<128, 256, 0, stream>>>(ws + WS_SCORES, ws + WS_SCR, mask, ws + WS_QABS,
                                          ws + WS_CKVT, ws + WS_QR, ws + WS_KRT);
  // p @ cKV aggregation: partials then reduce (+ new-token term)
  agg_part<<<dim3(NC, 4, 4), 256, 0, stream>>>(cKV, ws + WS_SCORES, ws + WS_AGGP,
                                               tlen, NC);
  agg_reduce<<<256, 256, 0, stream>>>(ws + WS_AGGP, ws + WS_SCORES, ws + WS_CKVT,
                                      ws + WS_AGG, NC);
  // apply W_UV then W_O
  out1_kernel<<<dim3(32, 8), 256, 0, stream>>>(ws + WS_AGG, W_UV_C, ws + WS_ATTN);
  gemv_atomic<<<dim3(128, 8), 256, 0, stream>>>(ws + WS_ATTN, W_O, ws + WS_OUTF, 4096, 4096, 512);
  // f32 output + cache tails
  finalize_kernel<<<104, 256, 0, stream>>>(ws + WS_OUTF, ws + WS_CKVT, ws + WS_KRT, out0);
}